// Round 1
// baseline (168.267 us; speedup 1.0000x reference)
//
#include <hip/hip_runtime.h>
#include <stdint.h>

typedef __bf16 bf16_t;
typedef bf16_t bf16x8 __attribute__((ext_vector_type(8)));
typedef float f32x4 __attribute__((ext_vector_type(4)));

#define DEV __device__ __forceinline__

DEV void gload_lds16(const void* g, void* l) {
  __builtin_amdgcn_global_load_lds(
      (__attribute__((address_space(1))) void*)(g),
      (__attribute__((address_space(3))) void*)(l), 16, 0, 0);
}

// ---------------- convert kernels ----------------
__global__ __launch_bounds__(256) void cvt2_kernel(
    const float* __restrict__ x, const float* __restrict__ q,
    bf16_t* __restrict__ xb, bf16_t* __restrict__ qb) {
  const float* s = blockIdx.y ? q : x;
  bf16_t* d = blockIdx.y ? qb : xb;
  int i = blockIdx.x * 256 + threadIdx.x;  // 524288 threads, 8 floats each
  if (i < 524288) {
    const float4* sp = (const float4*)s + (size_t)i * 2;
    float4 a = sp[0], b = sp[1];
    bf16x8 o;
    o[0] = (bf16_t)a.x; o[1] = (bf16_t)a.y; o[2] = (bf16_t)a.z; o[3] = (bf16_t)a.w;
    o[4] = (bf16_t)b.x; o[5] = (bf16_t)b.y; o[6] = (bf16_t)b.z; o[7] = (bf16_t)b.w;
    *(bf16x8*)(d + (size_t)i * 8) = o;
  }
}

__global__ __launch_bounds__(256) void cvtw_kernel(
    const float* __restrict__ Wq, const float* __restrict__ Wk,
    const float* __restrict__ Wv, const float* __restrict__ Wo,
    bf16_t* __restrict__ dst) {
  int y = blockIdx.y;
  const float* s = (y == 0) ? Wq : (y == 1) ? Wk : (y == 2) ? Wv : Wo;
  bf16_t* d = dst + (size_t)y * 262144;
  int i = blockIdx.x * 256 + threadIdx.x;  // 32768 threads, 8 floats each
  if (i < 32768) {
    const float4* sp = (const float4*)s + (size_t)i * 2;
    float4 a = sp[0], b = sp[1];
    bf16x8 o;
    o[0] = (bf16_t)a.x; o[1] = (bf16_t)a.y; o[2] = (bf16_t)a.z; o[3] = (bf16_t)a.w;
    o[4] = (bf16_t)b.x; o[5] = (bf16_t)b.y; o[6] = (bf16_t)b.z; o[7] = (bf16_t)b.w;
    *(bf16x8*)(d + (size_t)i * 8) = o;
  }
}

// ---------------- GEMM core: C[128x128] = A[128xK] * W[128xK]^T ----------------
// M=8192, N=512, K=512. LDS tiles [128 rows][64 bf16 =128B] XOR-swizzled
// (inner ^= (row&7)<<4), staged via global_load_lds with pre-swizzled source.
DEV void gemm_core(const bf16_t* __restrict__ A, const bf16_t* __restrict__ W,
                   char* smem, f32x4 (&acc)[4][4]) {
  const int tid = threadIdx.x;
  const int lane = tid & 63;
  const int wid = tid >> 6;
  const int wr = wid >> 1, wc = wid & 1;
  const int bx = blockIdx.x, by = blockIdx.y;

  uint32_t goffA[4], goffB[4], ldsoff[4];
#pragma unroll
  for (int c = 0; c < 4; ++c) {
    uint32_t o = (uint32_t)wid * 4096u + (uint32_t)c * 1024u + (uint32_t)lane * 16u;
    uint32_t row = o >> 7;
    uint32_t inner = (o & 127u) ^ ((row & 7u) << 4);
    goffA[c] = ((uint32_t)by * 128u + row) * 1024u + inner;  // byte offset, row stride 1024B
    goffB[c] = ((uint32_t)bx * 128u + row) * 1024u + inner;
    ldsoff[c] = o - (uint32_t)lane * 16u;  // wave-uniform LDS base
  }
  uint32_t offA[4][2], offB[4][2];
#pragma unroll
  for (int i = 0; i < 4; ++i)
#pragma unroll
    for (int kk = 0; kk < 2; ++kk) {
      uint32_t ra = (uint32_t)(wr * 64 + i * 16 + (lane & 15));
      offA[i][kk] = ra * 128u + (((uint32_t)kk * 64u + ((lane >> 4) * 16u)) ^ ((ra & 7u) << 4));
      uint32_t rb = (uint32_t)(wc * 64 + i * 16 + (lane & 15));
      offB[i][kk] = rb * 128u + (((uint32_t)kk * 64u + ((lane >> 4) * 16u)) ^ ((rb & 7u) << 4));
    }

  const char* Ab = (const char*)A;
  const char* Wb = (const char*)W;

  // prologue: stage tile 0 into buf 0
#pragma unroll
  for (int c = 0; c < 4; ++c) {
    gload_lds16(Ab + goffA[c], smem + ldsoff[c]);
    gload_lds16(Wb + goffB[c], smem + 16384 + ldsoff[c]);
  }
  asm volatile("s_waitcnt vmcnt(0)" ::: "memory");
  __syncthreads();

#pragma unroll 1
  for (int kt = 0; kt < 8; ++kt) {
    const int buf = kt & 1;
    char* cur = smem + buf * 32768;
    if (kt < 7) {
      char* nxt = smem + (buf ^ 1) * 32768;
      uint32_t gk = (uint32_t)(kt + 1) * 128u;
#pragma unroll
      for (int c = 0; c < 4; ++c) {
        gload_lds16(Ab + goffA[c] + gk, nxt + ldsoff[c]);
        gload_lds16(Wb + goffB[c] + gk, nxt + 16384 + ldsoff[c]);
      }
    }
    bf16x8 af[4][2], bfr[4][2];
#pragma unroll
    for (int kk = 0; kk < 2; ++kk)
#pragma unroll
      for (int i = 0; i < 4; ++i) {
        af[i][kk] = *(const bf16x8*)(cur + offA[i][kk]);
        bfr[i][kk] = *(const bf16x8*)(cur + 16384 + offB[i][kk]);
      }
#pragma unroll
    for (int kk = 0; kk < 2; ++kk)
#pragma unroll
      for (int mi = 0; mi < 4; ++mi)
#pragma unroll
        for (int nj = 0; nj < 4; ++nj)
          acc[mi][nj] = __builtin_amdgcn_mfma_f32_16x16x32_bf16(
              af[mi][kk], bfr[nj][kk], acc[mi][nj], 0, 0, 0);
    asm volatile("s_waitcnt vmcnt(0)" ::: "memory");
    __syncthreads();
  }
}

// QKV projection: z=0 -> Q=q@Wq^T+bq, z=1 -> K=x@Wk^T+bk, z=2 -> V=x@Wv^T+bv
// Output bf16 in [B*H][S][64] layout.
__global__ __launch_bounds__(256) void gemm_qkv_kernel(
    const bf16_t* __restrict__ xb, const bf16_t* __restrict__ qb,
    const bf16_t* __restrict__ Wb, const float* __restrict__ bq,
    const float* __restrict__ bk, const float* __restrict__ bv,
    bf16_t* __restrict__ Qh, bf16_t* __restrict__ Kh, bf16_t* __restrict__ Vh) {
  __shared__ char smem[65536];
  const int z = blockIdx.z;
  const bf16_t* A = (z == 0) ? qb : xb;
  const bf16_t* W = Wb + (size_t)z * 262144;
  const float* bias = (z == 0) ? bq : (z == 1) ? bk : bv;
  bf16_t* O = (z == 0) ? Qh : (z == 1) ? Kh : Vh;

  f32x4 acc[4][4] = {};
  gemm_core(A, W, smem, acc);

  const int lane = threadIdx.x & 63, wid = threadIdx.x >> 6;
  const int wr = wid >> 1, wc = wid & 1;
  const int colbase = blockIdx.x * 128 + wc * 64 + (lane & 15);
  const int rowbase = blockIdx.y * 128 + wr * 64 + ((lane >> 4) << 2);
#pragma unroll
  for (int nj = 0; nj < 4; ++nj) {
    int c = colbase + nj * 16;
    float bb = bias[c];
    int h = c >> 6, d = c & 63;
#pragma unroll
    for (int mi = 0; mi < 4; ++mi)
#pragma unroll
      for (int rr = 0; rr < 4; ++rr) {
        int r = rowbase + mi * 16 + rr;
        int b = r >> 11, s = r & 2047;
        O[((size_t)((b << 3) | h) * 2048 + s) * 64 + d] = (bf16_t)(acc[mi][nj][rr] + bb);
      }
  }
}

// Output projection: out = ctx @ Wo^T + bo, f32 [8192][512]
__global__ __launch_bounds__(256) void gemm_out_kernel(
    const bf16_t* __restrict__ ctx, const bf16_t* __restrict__ Wo,
    const float* __restrict__ bo, float* __restrict__ out) {
  __shared__ char smem[65536];
  f32x4 acc[4][4] = {};
  gemm_core(ctx, Wo, smem, acc);

  const int lane = threadIdx.x & 63, wid = threadIdx.x >> 6;
  const int wr = wid >> 1, wc = wid & 1;
  const int colbase = blockIdx.x * 128 + wc * 64 + (lane & 15);
  const int rowbase = blockIdx.y * 128 + wr * 64 + ((lane >> 4) << 2);
#pragma unroll
  for (int nj = 0; nj < 4; ++nj) {
    int c = colbase + nj * 16;
    float bb = bo[c];
#pragma unroll
    for (int mi = 0; mi < 4; ++mi)
#pragma unroll
      for (int rr = 0; rr < 4; ++rr) {
        int r = rowbase + mi * 16 + rr;
        out[(size_t)r * 512 + c] = acc[mi][nj][rr] + bb;
      }
  }
}

// ---------------- flash attention ----------------
// grid (16 q-tiles, 32 bh). 4 waves x 32 q-rows. KVBLK=64, 32 iterations.
__global__ __launch_bounds__(256) void attn_kernel(
    const bf16_t* __restrict__ Qh, const bf16_t* __restrict__ Kh,
    const bf16_t* __restrict__ Vh, bf16_t* __restrict__ ctx) {
  __shared__ char smem[32768];
  char* Kt = smem;          // [64 kv][128B d] swizzled
  char* Vt = smem + 8192;   // V^T: [64 d][128B kv] swizzled
  const int tid = threadIdx.x, lane = tid & 63, wid = tid >> 6;
  char* Pw = smem + 16384 + wid * 4096;  // per-wave P: [32 q][128B kv] swizzled
  const int qt = blockIdx.x, bh = blockIdx.y;

  const char* Kbase = (const char*)Kh + (size_t)bh * 262144;
  const char* Vbase = (const char*)Vh + (size_t)bh * 262144;
  const char* Qbase = (const char*)Qh + (size_t)bh * 262144;

  // Q fragments (held in registers for whole kernel)
  bf16x8 qf[2][2];
#pragma unroll
  for (int mi = 0; mi < 2; ++mi)
#pragma unroll
    for (int kk = 0; kk < 2; ++kk) {
      int qrow = qt * 128 + wid * 32 + mi * 16 + (lane & 15);
      qf[mi][kk] = *(const bf16x8*)(Qbase + (size_t)qrow * 128 + kk * 64 + ((lane >> 4) * 16));
    }

  uint32_t kgoff[2], klds[2];
#pragma unroll
  for (int c = 0; c < 2; ++c) {
    uint32_t o = (uint32_t)c * 4096u + (uint32_t)wid * 1024u + (uint32_t)lane * 16u;
    uint32_t row = o >> 7;
    uint32_t inner = (o & 127u) ^ ((row & 7u) << 4);
    kgoff[c] = row * 128u + inner;
    klds[c] = o - (uint32_t)lane * 16u;
  }

  f32x4 o_acc[2][4] = {};
  float m_run[2][4], l_run[2][4];
#pragma unroll
  for (int mi = 0; mi < 2; ++mi)
#pragma unroll
    for (int rr = 0; rr < 4; ++rr) { m_run[mi][rr] = -3.0e38f; l_run[mi][rr] = 0.f; }

  const uint32_t vgo = (uint32_t)lane * 128u + (uint32_t)wid * 16u;

#pragma unroll 1
  for (int t = 0; t < 32; ++t) {
    const char* Ks = Kbase + (size_t)t * 8192;
    const char* Vs = Vbase + (size_t)t * 8192;
    __syncthreads();  // previous iteration's LDS reads done
    // stage K (async to LDS, pre-swizzled source)
    gload_lds16(Ks + kgoff[0], Kt + klds[0]);
    gload_lds16(Ks + kgoff[1], Kt + klds[1]);
    // stage V transposed: lane=kv row, wave covers 8 d-cols per round
    bf16x8 v0 = *(const bf16x8*)(Vs + vgo);
    bf16x8 v1 = *(const bf16x8*)(Vs + vgo + 64);
#pragma unroll
    for (int e = 0; e < 8; ++e) {
      uint32_t d0 = (uint32_t)wid * 8u + (uint32_t)e;
      *(bf16_t*)(Vt + d0 * 128u + (((uint32_t)lane * 2u) ^ ((d0 & 7u) << 4))) = v0[e];
      uint32_t d1 = d0 + 32u;
      *(bf16_t*)(Vt + d1 * 128u + (((uint32_t)lane * 2u) ^ ((d1 & 7u) << 4))) = v1[e];
    }
    asm volatile("s_waitcnt vmcnt(0)" ::: "memory");
    __syncthreads();

    // S = Q K^T  (C row = q, col = kv)
    f32x4 sA[2][4] = {};
#pragma unroll
    for (int kk = 0; kk < 2; ++kk) {
      bf16x8 kf[4];
#pragma unroll
      for (int nj = 0; nj < 4; ++nj) {
        uint32_t row = (uint32_t)(nj * 16 + (lane & 15));
        kf[nj] = *(const bf16x8*)(Kt + row * 128u +
                 (((uint32_t)kk * 64u + ((lane >> 4) * 16u)) ^ ((row & 7u) << 4)));
      }
#pragma unroll
      for (int mi = 0; mi < 2; ++mi)
#pragma unroll
        for (int nj = 0; nj < 4; ++nj)
          sA[mi][nj] = __builtin_amdgcn_mfma_f32_16x16x32_bf16(qf[mi][kk], kf[nj], sA[mi][nj], 0, 0, 0);
    }

    // online softmax (row = mi*16 + (lane>>4)*4 + rr; 64 cols across 16 lanes x 4 nj)
#pragma unroll
    for (int mi = 0; mi < 2; ++mi) {
#pragma unroll
      for (int rr = 0; rr < 4; ++rr) {
        float x0 = sA[mi][0][rr] * 0.125f;
        float x1 = sA[mi][1][rr] * 0.125f;
        float x2 = sA[mi][2][rr] * 0.125f;
        float x3 = sA[mi][3][rr] * 0.125f;
        float mx = fmaxf(fmaxf(x0, x1), fmaxf(x2, x3));
        mx = fmaxf(mx, __shfl_xor(mx, 1));
        mx = fmaxf(mx, __shfl_xor(mx, 2));
        mx = fmaxf(mx, __shfl_xor(mx, 4));
        mx = fmaxf(mx, __shfl_xor(mx, 8));
        float mold = m_run[mi][rr];
        float mnew = fmaxf(mold, mx);
        float sc = __expf(mold - mnew);
        float p0 = __expf(x0 - mnew);
        float p1 = __expf(x1 - mnew);
        float p2 = __expf(x2 - mnew);
        float p3 = __expf(x3 - mnew);
        float ps = (p0 + p1) + (p2 + p3);
        ps += __shfl_xor(ps, 1);
        ps += __shfl_xor(ps, 2);
        ps += __shfl_xor(ps, 4);
        ps += __shfl_xor(ps, 8);
        m_run[mi][rr] = mnew;
        l_run[mi][rr] = l_run[mi][rr] * sc + ps;
#pragma unroll
        for (int dj = 0; dj < 4; ++dj) o_acc[mi][dj][rr] *= sc;
        uint32_t prow = (uint32_t)(mi * 16 + ((lane >> 4) << 2) + rr);
        char* pr = Pw + prow * 128u;
        uint32_t sw = (prow & 7u) << 4;
        uint32_t cb = (uint32_t)(lane & 15) * 2u;
        *(bf16_t*)(pr + ((cb)       ^ sw)) = (bf16_t)p0;
        *(bf16_t*)(pr + ((cb + 32u) ^ sw)) = (bf16_t)p1;
        *(bf16_t*)(pr + ((cb + 64u) ^ sw)) = (bf16_t)p2;
        *(bf16_t*)(pr + ((cb + 96u) ^ sw)) = (bf16_t)p3;
      }
    }
    // P writes are read back by other lanes of the SAME wave: wait + fence
    asm volatile("s_waitcnt lgkmcnt(0)" ::: "memory");
    __builtin_amdgcn_sched_barrier(0);

    // O += P V   (A = P [q][kv], B = V via V^T [d][kv])
#pragma unroll
    for (int kv = 0; kv < 2; ++kv) {
      bf16x8 pf[2], vf[4];
#pragma unroll
      for (int mi = 0; mi < 2; ++mi) {
        uint32_t row = (uint32_t)(mi * 16 + (lane & 15));
        pf[mi] = *(const bf16x8*)(Pw + row * 128u +
                 (((uint32_t)kv * 64u + ((lane >> 4) * 16u)) ^ ((row & 7u) << 4)));
      }
#pragma unroll
      for (int dj = 0; dj < 4; ++dj) {
        uint32_t row = (uint32_t)(dj * 16 + (lane & 15));
        vf[dj] = *(const bf16x8*)(Vt + row * 128u +
                 (((uint32_t)kv * 64u + ((lane >> 4) * 16u)) ^ ((row & 7u) << 4)));
      }
#pragma unroll
      for (int mi = 0; mi < 2; ++mi)
#pragma unroll
        for (int dj = 0; dj < 4; ++dj)
          o_acc[mi][dj] = __builtin_amdgcn_mfma_f32_16x16x32_bf16(pf[mi], vf[dj], o_acc[mi][dj], 0, 0, 0);
    }
  }

  // epilogue: divide by row sum, write ctx [B][S][H*64] bf16
  const int b = bh >> 3, h = bh & 7;
#pragma unroll
  for (int mi = 0; mi < 2; ++mi)
#pragma unroll
    for (int rr = 0; rr < 4; ++rr) {
      float inv = 1.0f / l_run[mi][rr];
      int qrow = qt * 128 + wid * 32 + mi * 16 + ((lane >> 4) << 2) + rr;
      size_t base = ((size_t)(b * 2048 + qrow)) * 512 + h * 64 + (lane & 15);
#pragma unroll
      for (int dj = 0; dj < 4; ++dj)
        ctx[base + dj * 16] = (bf16_t)(o_acc[mi][dj][rr] * inv);
    }
}

extern "C" void kernel_launch(void* const* d_in, const int* in_sizes, int n_in,
                              void* d_out, int out_size, void* d_ws, size_t ws_size,
                              hipStream_t stream) {
  const float* x  = (const float*)d_in[0];
  const float* q  = (const float*)d_in[1];
  const float* Wq = (const float*)d_in[2];
  const float* bq = (const float*)d_in[3];
  const float* Wk = (const float*)d_in[4];
  const float* bk = (const float*)d_in[5];
  const float* Wv = (const float*)d_in[6];
  const float* bv = (const float*)d_in[7];
  const float* Wo = (const float*)d_in[8];
  const float* bo = (const float*)d_in[9];

  char* ws = (char*)d_ws;
  bf16_t* xb  = (bf16_t*)(ws + 0);          // 8 MB
  bf16_t* qb  = (bf16_t*)(ws + 8388608);    // 8 MB
  bf16_t* Wb  = (bf16_t*)(ws + 16777216);   // 4 x 512KB (Wq,Wk,Wv,Wo)
  bf16_t* Qh  = (bf16_t*)(ws + 18874368);   // 8 MB [32][2048][64]
  bf16_t* Kh  = (bf16_t*)(ws + 27262976);   // 8 MB
  bf16_t* Vh  = (bf16_t*)(ws + 35651584);   // 8 MB
  bf16_t* ctx = (bf16_t*)(ws + 44040192);   // 8 MB  (total 50 MB)

  cvt2_kernel<<<dim3(2048, 2), 256, 0, stream>>>(x, q, xb, qb);
  cvtw_kernel<<<dim3(128, 4), 256, 0, stream>>>(Wq, Wk, Wv, Wo, Wb);
  gemm_qkv_kernel<<<dim3(4, 64, 3), 256, 0, stream>>>(xb, qb, Wb, bq, bk, bv, Qh, Kh, Vh);
  attn_kernel<<<dim3(16, 32), 256, 0, stream>>>(Qh, Kh, Vh, ctx);
  gemm_out_kernel<<<dim3(4, 64), 256, 0, stream>>>(ctx, Wb + 3 * 262144, bo, (float*)d_out);
}